// Round 6
// baseline (907.173 us; speedup 1.0000x reference)
//
#include <hip/hip_runtime.h>
#include <hip/hip_bf16.h>

#define BS 16384    // B*S tokens
#define HDIM 4096   // hidden dim
#define NE 64       // experts
#define KC 64       // K-chunk per LDS stage
#define TT 32       // tokens per block (K1)
#define CAP 512     // max boundary candidates per expert
#define DELTA 2e-3f // bf16-split GEMM error margin (actual err ~2e-5 rms)

typedef __bf16 bf16x8 __attribute__((ext_vector_type(8)));
typedef float f32x4 __attribute__((ext_vector_type(4)));
union Frag { uint4 q; bf16x8 v; };

__device__ inline unsigned f2key(float f) {
    unsigned u = __float_as_uint(f);
    return (u & 0x80000000u) ? ~u : (u | 0x80000000u);
}
__device__ inline float key2f(unsigned k) {
    unsigned u = (k & 0x80000000u) ? (k ^ 0x80000000u) : ~k;
    return __uint_as_float(u);
}
__device__ inline unsigned pack_hi(float a, float b) {  // bf16(a)|bf16(b)<<16 (trunc)
    return (__float_as_uint(a) >> 16) | (__float_as_uint(b) & 0xFFFF0000u);
}
__device__ inline float bf16_resid(float a) {  // a - trunc_bf16(a), exact
    return a - __uint_as_float(__float_as_uint(a) & 0xFFFF0000u);
}

// ---------------------------------------------------------------------------
// K0: convert W -> bf16 hi/lo; zero token-major winner bitmap.
// ---------------------------------------------------------------------------
__global__ __launch_bounds__(256) void k0_init(const float* __restrict__ W,
                                               unsigned short* __restrict__ Wh,
                                               unsigned short* __restrict__ Wl,
                                               unsigned long long* __restrict__ win_t) {
    const int gtid = blockIdx.x * 256 + threadIdx.x;  // 0..65535
    const size_t f = (size_t)gtid * 4;                // covers NE*HDIM = 262144
    float4 w = *(const float4*)(W + f);
    uint2 hh, ll;
    hh.x = pack_hi(w.x, w.y); hh.y = pack_hi(w.z, w.w);
    ll.x = pack_hi(bf16_resid(w.x), bf16_resid(w.y));
    ll.y = pack_hi(bf16_resid(w.z), bf16_resid(w.w));
    *(uint2*)(Wh + f) = hh;
    *(uint2*)(Wl + f) = ll;
    if (gtid < BS) win_t[gtid] = 0ull;
}

// ---------------------------------------------------------------------------
// K1: logits = A @ W^T via bf16-split MFMA (AhBh+AlBh+AhBl, 16x16x32).
// 32 tok x 64 exp tile, 256 thr (4 waves), grid 512 -> 2 blocks/CU.
// Double-buffered LDS, one __syncthreads/chunk, register prefetch.
// Epilogue: Lg token-major + KeyT expert-major via LDS transpose.
// (unchanged from round 5 — control variable for this round's k2 experiment)
// ---------------------------------------------------------------------------
__global__ __launch_bounds__(256, 2) void k1_gemm(const float* __restrict__ A,
                                                  const unsigned short* __restrict__ Wh,
                                                  const unsigned short* __restrict__ Wl,
                                                  float* __restrict__ Lg,
                                                  unsigned* __restrict__ KeyT) {
    __shared__ __align__(16) unsigned short sbuf[2 * 13824];

    const int tid = threadIdx.x;
    const int T0 = blockIdx.x * TT;

    const int arow = tid >> 3, aseg = tid & 7;

    const int lane = tid & 63, w = tid >> 6;
    const int m = lane & 15, q = lane >> 4;
    const int wm = w & 1;
    const int wn = w >> 1;

    const float* Aprow = A + (size_t)(T0 + arow) * HDIM + aseg * 8;

    f32x4 acc[2] = {{0.f, 0.f, 0.f, 0.f}, {0.f, 0.f, 0.f, 0.f}};

    float4 pa0 = *(const float4*)(Aprow);
    float4 pa1 = *(const float4*)(Aprow + 4);
    uint4 pwh[2], pwl[2];
#pragma unroll
    for (int i = 0; i < 2; ++i) {
        const int u = i * 256 + tid;
        const int r = u >> 3, blk = u & 7;
        pwh[i] = *(const uint4*)(Wh + (size_t)r * HDIM + blk * 8);
        pwl[i] = *(const uint4*)(Wl + (size_t)r * HDIM + blk * 8);
    }

    {
        unsigned short* B = sbuf;
        uint4 H, L;
        H.x = pack_hi(pa0.x, pa0.y); H.y = pack_hi(pa0.z, pa0.w);
        H.z = pack_hi(pa1.x, pa1.y); H.w = pack_hi(pa1.z, pa1.w);
        L.x = pack_hi(bf16_resid(pa0.x), bf16_resid(pa0.y));
        L.y = pack_hi(bf16_resid(pa0.z), bf16_resid(pa0.w));
        L.z = pack_hi(bf16_resid(pa1.x), bf16_resid(pa1.y));
        L.w = pack_hi(bf16_resid(pa1.z), bf16_resid(pa1.w));
        *(uint4*)(B + arow * 72 + aseg * 8) = H;
        *(uint4*)(B + 2304 + arow * 72 + aseg * 8) = L;
#pragma unroll
        for (int i = 0; i < 2; ++i) {
            const int u = i * 256 + tid;
            const int r = u >> 3, blk = u & 7;
            *(uint4*)(B + 4608 + r * 72 + blk * 8) = pwh[i];
            *(uint4*)(B + 9216 + r * 72 + blk * 8) = pwl[i];
        }
    }

    for (int c = 0; c < HDIM / KC; ++c) {
        if (c + 1 < HDIM / KC) {
            const int c0 = (c + 1) * KC;
            pa0 = *(const float4*)(Aprow + c0);
            pa1 = *(const float4*)(Aprow + c0 + 4);
#pragma unroll
            for (int i = 0; i < 2; ++i) {
                const int u = i * 256 + tid;
                const int r = u >> 3, blk = u & 7;
                pwh[i] = *(const uint4*)(Wh + (size_t)r * HDIM + c0 + blk * 8);
                pwl[i] = *(const uint4*)(Wl + (size_t)r * HDIM + c0 + blk * 8);
            }
        }
        __syncthreads();
        {
            const unsigned short* B = sbuf + (c & 1) * 13824;
            const unsigned short* Ash = B + (wm * 16 + m) * 72;
            const unsigned short* Asl = Ash + 2304;
#pragma unroll
            for (int kh = 0; kh < 2; ++kh) {
                const int ko = kh * 32 + q * 8;
                Frag ah, al;
                ah.q = *(const uint4*)(Ash + ko);
                al.q = *(const uint4*)(Asl + ko);
#pragma unroll
                for (int nt = 0; nt < 2; ++nt) {
                    const int er = wn * 32 + nt * 16 + m;
                    Frag bh, bl;
                    bh.q = *(const uint4*)(B + 4608 + er * 72 + ko);
                    bl.q = *(const uint4*)(B + 9216 + er * 72 + ko);
                    acc[nt] = __builtin_amdgcn_mfma_f32_16x16x32_bf16(ah.v, bh.v, acc[nt], 0, 0, 0);
                    acc[nt] = __builtin_amdgcn_mfma_f32_16x16x32_bf16(al.v, bh.v, acc[nt], 0, 0, 0);
                    acc[nt] = __builtin_amdgcn_mfma_f32_16x16x32_bf16(ah.v, bl.v, acc[nt], 0, 0, 0);
                }
            }
        }
        if (c + 1 < HDIM / KC) {
            unsigned short* B = sbuf + ((c + 1) & 1) * 13824;
            uint4 H, L;
            H.x = pack_hi(pa0.x, pa0.y); H.y = pack_hi(pa0.z, pa0.w);
            H.z = pack_hi(pa1.x, pa1.y); H.w = pack_hi(pa1.z, pa1.w);
            L.x = pack_hi(bf16_resid(pa0.x), bf16_resid(pa0.y));
            L.y = pack_hi(bf16_resid(pa0.z), bf16_resid(pa0.w));
            L.z = pack_hi(bf16_resid(pa1.x), bf16_resid(pa1.y));
            L.w = pack_hi(bf16_resid(pa1.z), bf16_resid(pa1.w));
            *(uint4*)(B + arow * 72 + aseg * 8) = H;
            *(uint4*)(B + 2304 + arow * 72 + aseg * 8) = L;
#pragma unroll
            for (int i = 0; i < 2; ++i) {
                const int u = i * 256 + tid;
                const int r = u >> 3, blk = u & 7;
                *(uint4*)(B + 4608 + r * 72 + blk * 8) = pwh[i];
                *(uint4*)(B + 9216 + r * 72 + blk * 8) = pwl[i];
            }
        }
    }

    __syncthreads();
    float* Sc = (float*)sbuf;  // [32][68]
#pragma unroll
    for (int nt = 0; nt < 2; ++nt) {
        const int e = wn * 32 + nt * 16 + m;
#pragma unroll
        for (int r = 0; r < 4; ++r) {
            const int tl = wm * 16 + q * 4 + r;
            const float v = acc[nt][r];
            Sc[tl * 68 + e] = v;
            Lg[(size_t)(T0 + tl) * NE + e] = v;
        }
    }
    __syncthreads();
    {
        const int e = tid >> 2, jj = tid & 3;
        unsigned kk[8];
#pragma unroll
        for (int r = 0; r < 8; ++r) kk[r] = f2key(Sc[(jj * 8 + r) * 68 + e]);
        uint4 v0 = {kk[0], kk[1], kk[2], kk[3]}, v1 = {kk[4], kk[5], kk[6], kk[7]};
        unsigned* dst = KeyT + (size_t)e * BS + T0 + jj * 8;
        *(uint4*)dst = v0;
        *(uint4*)(dst + 4) = v1;
    }
}

// ---------------------------------------------------------------------------
// K2 (REWRITTEN): per-expert top-C bin via 14-bit-prefix LDS histogram +
// one barrier-light block suffix-scan (in-wave shfl_down scans + 16 wave
// totals). Replaces the 32-bit binary search (96 barriers -> ~6).
// Cuts at bin edges +/- 2*DELTA; then one classify pass: count definite-ins
// (> khi), collect candidates in [klo, khi].
// ---------------------------------------------------------------------------
__global__ __launch_bounds__(1024) void k2_select(const unsigned* __restrict__ KeyT,
                                                  const int* __restrict__ Cptr,
                                                  unsigned* __restrict__ khi_g,
                                                  int* __restrict__ needed_g,
                                                  int* __restrict__ ncand_g,
                                                  int* __restrict__ cand_g) {
    const int e = blockIdx.x, tid = threadIdx.x;
    const int wid = tid >> 6, lane = tid & 63;
    const int C = *Cptr;
    const unsigned* col = KeyT + (size_t)e * BS;

    __shared__ unsigned hist[16384];  // 64 KB: 14-bit key-prefix bins
    __shared__ int wtot[16], wab[16];
    __shared__ int sred[16];
    __shared__ int s_B, s_nc, s_tot;

    unsigned key[16];
#pragma unroll
    for (int j = 0; j < 16; ++j) key[j] = col[j * 1024 + tid];

    // zero histogram (uint4 stores)
    {
        uint4 z = {0, 0, 0, 0};
#pragma unroll
        for (int i = 0; i < 4; ++i) *(uint4*)&hist[(i * 1024 + tid) * 4] = z;
    }
    if (tid == 0) { s_nc = 0; s_B = 0; }
    __syncthreads();

#pragma unroll
    for (int j = 0; j < 16; ++j) atomicAdd(&hist[key[j] >> 18], 1u);
    __syncthreads();

    // per-thread chunk total over bins [tid*16, tid*16+16)
    int loc = 0;
#pragma unroll
    for (int k = 0; k < 16; ++k) loc += (int)hist[tid * 16 + k];

    // in-wave inclusive suffix scan (higher lane = higher bins)
    int sfx = loc;
#pragma unroll
    for (int off = 1; off < 64; off <<= 1) {
        const int v = __shfl_down(sfx, off);
        if (lane + off < 64) sfx += v;
    }
    if (lane == 0) wtot[wid] = sfx;  // wave total
    __syncthreads();
    if (wid == 0 && lane < 16) {
        int v = wtot[lane];
        int s = v;
#pragma unroll
        for (int off = 1; off < 16; off <<= 1) {
            const int u = __shfl_down(s, off);
            if (lane + off < 16) s += u;
        }
        wab[lane] = s - v;  // strictly-above-wave total
    }
    __syncthreads();

    // crossing chunk: cum_excl < C <= cum_incl
    const int cum_incl = sfx + wab[wid];
    const int cum_excl = cum_incl - loc;
    if (cum_excl < C && cum_incl >= C) {
        int run = cum_excl;
        for (int k = 15; k >= 0; --k) {
            run += (int)hist[tid * 16 + k];
            if (run >= C) { s_B = tid * 16 + k; break; }
        }
    }
    __syncthreads();

    const int B = s_B;
    const float vlo = key2f((unsigned)B << 18);
    unsigned khi;
    if (B >= 16383) khi = 0xFFFFFFFFu;
    else khi = f2key(key2f((unsigned)(B + 1) << 18) + 2.0f * DELTA);
    const unsigned klo = f2key(vlo - 2.0f * DELTA);

    // classify pass
    int nd = 0;
#pragma unroll
    for (int j = 0; j < 16; ++j) nd += (key[j] > khi);
#pragma unroll
    for (int off = 32; off; off >>= 1) nd += __shfl_xor(nd, off);
    if (lane == 0) sred[wid] = nd;
    __syncthreads();
    if (wid == 0) {
        int v = (lane < 16) ? sred[lane] : 0;
        v += __shfl_xor(v, 1); v += __shfl_xor(v, 2);
        v += __shfl_xor(v, 4); v += __shfl_xor(v, 8);
        if (lane == 0) s_tot = v;
    }
#pragma unroll
    for (int j = 0; j < 16; ++j) {
        if (key[j] >= klo && key[j] <= khi) {
            const int pos = atomicAdd(&s_nc, 1);
            if (pos < CAP) cand_g[(size_t)e * CAP + pos] = j * 1024 + tid;
        }
    }
    __syncthreads();
    if (tid == 0) {
        khi_g[e] = khi;
        needed_g[e] = C - s_tot;
        ncand_g[e] = (s_nc < CAP) ? s_nc : CAP;
    }
}

// ---------------------------------------------------------------------------
// K2b: exact fp64 dots for boundary candidates (wave-parallel); pick
// top-'needed' by (fp64 desc, idx asc); set bits in token-major bitmap.
// ---------------------------------------------------------------------------
__global__ __launch_bounds__(256) void k2b_resolve(const float* __restrict__ A,
                                                   const float* __restrict__ W,
                                                   const int* __restrict__ needed_g,
                                                   const int* __restrict__ ncand_g,
                                                   const int* __restrict__ cand_g,
                                                   unsigned long long* __restrict__ win_t) {
    const int e = blockIdx.x, tid = threadIdx.x, w = tid >> 6, lane = tid & 63;
    int n = ncand_g[e]; if (n > CAP) n = CAP;
    int need = needed_g[e]; if (need > n) need = n; if (need < 0) need = 0;
    __shared__ double sval[CAP];
    __shared__ int sidx[CAP];
    const float* Wr = W + (size_t)e * HDIM;
    for (int c = w; c < n; c += 4) {
        const int t = cand_g[(size_t)e * CAP + c];
        const float* Ar = A + (size_t)t * HDIM;
        double ps = 0.0;
#pragma unroll 8
        for (int j = 0; j < HDIM / 64; ++j)
            ps += (double)Ar[j * 64 + lane] * (double)Wr[j * 64 + lane];
#pragma unroll
        for (int off = 32; off; off >>= 1) ps += __shfl_xor(ps, off);
        if (lane == 0) { sval[c] = ps; sidx[c] = t; }
    }
    __syncthreads();
    if (tid == 0) {
        for (int s = 0; s < need; ++s) {
            int best = -1;
            for (int c = 0; c < n; ++c) {
                if (sidx[c] < 0) continue;
                if (best < 0 || sval[c] > sval[best] ||
                    (sval[c] == sval[best] && sidx[c] < sidx[best]))
                    best = c;
            }
            const int t = sidx[best];
            atomicOr(&win_t[t], 1ull << e);
            sidx[best] = -1;
        }
    }
}

// ---------------------------------------------------------------------------
// K3: per-token softmax+mask+renorm (single reduction pass; |logit| small).
// map = (key > khi) | token-major winner bit. Per-block fp64 importance
// partials (no global atomics).
// ---------------------------------------------------------------------------
__global__ __launch_bounds__(256) void k3_softmax(const float* __restrict__ Lg,
                                                  const unsigned* __restrict__ khi_g,
                                                  const unsigned long long* __restrict__ win_t,
                                                  float* __restrict__ probs,
                                                  float* __restrict__ out_map,
                                                  double* __restrict__ imp_partial) {
    const int tid = threadIdx.x, w = tid >> 6, e = tid & 63, b = blockIdx.x;
    __shared__ unsigned skhi[64];
    __shared__ double sim[4][64];
    if (tid < 64) skhi[tid] = khi_g[tid];
    __syncthreads();
    const unsigned kh = skhi[e];
    double accim = 0.0;
#pragma unroll
    for (int it = 0; it < 16; ++it) {
        const int t = b * 64 + it * 4 + w;
        const float x = Lg[(size_t)t * NE + e];
        const unsigned key = f2key(x);
        float mfl;
        if (key > kh) mfl = 1.f;
        else mfl = (float)((win_t[t] >> e) & 1ull);
        const float ev = expf(x);
        const float evm = ev * mfl;
        float s1 = ev, s2 = evm;
#pragma unroll
        for (int off = 32; off; off >>= 1) {
            s1 += __shfl_xor(s1, off);
            s2 += __shfl_xor(s2, off);
        }
        const float o = evm / (s2 + 1e-6f * s1);
        probs[(size_t)t * NE + e] = o;
        out_map[(size_t)t * NE + e] = mfl;
        accim += (double)o;
    }
    sim[w][e] = accim;
    __syncthreads();
    if (w == 0)
        imp_partial[(size_t)b * NE + e] = sim[0][e] + sim[1][e] + sim[2][e] + sim[3][e];
}

// ---------------------------------------------------------------------------
// K4: reduce importance partials; aux = (std(imp,ddof=1)/(mean+eps))^2.
// ---------------------------------------------------------------------------
__global__ __launch_bounds__(64) void k4_aux(const double* __restrict__ imp_partial,
                                             float* __restrict__ out_aux) {
    const int e = threadIdx.x;
    double v = 0.0;
    for (int b = 0; b < 256; ++b) v += imp_partial[(size_t)b * NE + e];
    double s = v;
#pragma unroll
    for (int off = 32; off; off >>= 1) s += __shfl_xor(s, off);
    const double mean = s / 64.0;
    const double d = v - mean;
    double ss = d * d;
#pragma unroll
    for (int off = 32; off; off >>= 1) ss += __shfl_xor(ss, off);
    if (e == 0) {
        const double var = ss / 63.0;
        const double dn = mean + 1e-6;
        out_aux[0] = (float)(var / (dn * dn));
    }
}

extern "C" void kernel_launch(void* const* d_in, const int* in_sizes, int n_in,
                              void* d_out, int out_size, void* d_ws, size_t ws_size,
                              hipStream_t stream) {
    const float* A = (const float*)d_in[0];
    const float* W = (const float*)d_in[1];
    const int* Cptr = (const int*)d_in[2];

    float* out_probs = (float*)d_out;
    float* out_map = out_probs + (size_t)BS * NE;
    float* out_aux = out_map + (size_t)BS * NE;

    char* wsb = (char*)d_ws;
    float*              Lg     = (float*)wsb;                                  // 4 MB
    unsigned*           KeyT   = (unsigned*)(wsb + (4ull << 20));              // 4 MB
    unsigned short*     Wh     = (unsigned short*)(wsb + (8ull << 20));        // 512 KB
    unsigned short*     Wl     = (unsigned short*)(wsb + (8ull << 20) + (512ull << 10));
    int*                cand   = (int*)(wsb + (9ull << 20));                   // 128 KB
    unsigned long long* win_t  = (unsigned long long*)(wsb + (9ull << 20) + (128ull << 10)); // 128 KB
    unsigned*           khi_g  = (unsigned*)(wsb + (9ull << 20) + (256ull << 10));
    int*                needed = (int*)(wsb + (9ull << 20) + (257ull << 10));
    int*                ncand  = (int*)(wsb + (9ull << 20) + (258ull << 10));
    double*             imp_p  = (double*)(wsb + (9ull << 20) + (512ull << 10)); // 128 KB

    k0_init<<<256, 256, 0, stream>>>(W, Wh, Wl, win_t);
    k1_gemm<<<BS / TT, 256, 0, stream>>>(A, Wh, Wl, Lg, KeyT);
    k2_select<<<NE, 1024, 0, stream>>>(KeyT, Cptr, khi_g, needed, ncand, cand);
    k2b_resolve<<<NE, 256, 0, stream>>>(A, W, needed, ncand, cand, win_t);
    k3_softmax<<<BS / 64, 256, 0, stream>>>(Lg, khi_g, win_t, out_probs, out_map, imp_p);
    k4_aux<<<1, 64, 0, stream>>>(imp_p, out_aux);
}